// Round 1
// baseline (15062.463 us; speedup 1.0000x reference)
//
#include <hip/hip_runtime.h>
#include <cstddef>

// ---------------------------------------------------------------------------
// TrainModel: CNN -> BiLSTM encoder -> attention decoder.  fp32 baseline.
// B=16, image 64x512x1, Hp=8, Wp=64, ENC_H=256, DEC_H=512, ATT=512, VOCAB=504
// ---------------------------------------------------------------------------

#define TDEC 150
#define TLAB 151

__device__ __forceinline__ float sigm(float x) { return 1.0f / (1.0f + __expf(-x)); }
__device__ __forceinline__ float tanhfast(float x) {
  float ax = fabsf(x);
  float e = __expf(-2.0f * ax);       // in (0,1], no overflow/NaN
  float t = (1.0f - e) / (1.0f + e);
  return x < 0.0f ? -t : t;
}

// ---------------- fused conv3x3(SAME) + relu + maxpool2x2 ------------------
__global__ __launch_bounds__(256) void conv_pool(
    const float* __restrict__ x, const float* __restrict__ W,
    const float* __restrict__ bias, float* __restrict__ y,
    int Hin, int Win, int Cin, int Cout)
{
  int Hout = Hin >> 1, Wout = Win >> 1;
  int cg = Cout >> 3;
  int idx = blockIdx.x * 256 + threadIdx.x;
  int total = 16 * Hout * Wout * cg;
  if (idx >= total) return;
  int g = idx % cg; int r = idx / cg;
  int pw = r % Wout; r /= Wout;
  int ph = r % Hout; int b = r / Hout;
  int co = g * 8;
  int h0 = ph * 2, w0 = pw * 2;
  float acc[4][8];
#pragma unroll
  for (int p = 0; p < 4; p++)
#pragma unroll
    for (int cc = 0; cc < 8; cc++) acc[p][cc] = 0.0f;
  bool interior = (h0 >= 1) && (h0 + 3 < Hin) && (w0 >= 1) && (w0 + 3 < Win);
  const int rs = Win * Cin;
  for (int ci = 0; ci < Cin; ci++) {
    float patch[5][5];
    if (interior) {
      const float* xp = x + ((b * Hin + (h0 - 1)) * Win + (w0 - 1)) * Cin + ci;
#pragma unroll
      for (int rr = 0; rr < 5; rr++)
#pragma unroll
        for (int cc = 0; cc < 5; cc++)
          patch[rr][cc] = xp[rr * rs + cc * Cin];
    } else {
#pragma unroll
      for (int rr = 0; rr < 5; rr++) {
        int ih = h0 - 1 + rr;
#pragma unroll
        for (int cc = 0; cc < 5; cc++) {
          int iw = w0 - 1 + cc;
          patch[rr][cc] = (ih >= 0 && ih < Hin && iw >= 0 && iw < Win)
                              ? x[((b * Hin + ih) * Win + iw) * Cin + ci] : 0.0f;
        }
      }
    }
#pragma unroll
    for (int ky = 0; ky < 3; ky++) {
#pragma unroll
      for (int kx = 0; kx < 3; kx++) {
        const float* wp = W + (((ky * 3 + kx) * Cin) + ci) * Cout + co;
        float4 wa = *(const float4*)wp;
        float4 wb = *(const float4*)(wp + 4);
        float w8[8] = {wa.x, wa.y, wa.z, wa.w, wb.x, wb.y, wb.z, wb.w};
#pragma unroll
        for (int py = 0; py < 2; py++)
#pragma unroll
          for (int px = 0; px < 2; px++) {
            float iv = patch[py + ky][px + kx];
#pragma unroll
            for (int cc = 0; cc < 8; cc++) acc[py * 2 + px][cc] += iv * w8[cc];
          }
      }
    }
  }
  float* yp = y + ((b * Hout + ph) * Wout + pw) * Cout + co;
#pragma unroll
  for (int cc = 0; cc < 8; cc++) {
    float m = fmaxf(fmaxf(acc[0][cc], acc[1][cc]), fmaxf(acc[2][cc], acc[3][cc]));
    yp[cc] = fmaxf(m + bias[co + cc], 0.0f);   // relu(max+b) == max(relu(+b))
  }
}

// ---------------- conv3x3(SAME) + relu (no pool) ---------------------------
__global__ __launch_bounds__(256) void conv_nopool(
    const float* __restrict__ x, const float* __restrict__ W,
    const float* __restrict__ bias, float* __restrict__ y,
    int H, int Wd, int Cin, int Cout)
{
  int cg = Cout >> 3;
  int idx = blockIdx.x * 256 + threadIdx.x;
  int total = 16 * H * Wd * cg;
  if (idx >= total) return;
  int g = idx % cg; int r = idx / cg;
  int w = r % Wd; r /= Wd;
  int h = r % H; int b = r / H;
  int co = g * 8;
  float acc[8];
#pragma unroll
  for (int cc = 0; cc < 8; cc++) acc[cc] = 0.0f;
  bool interior = (h >= 1) && (h + 1 < H) && (w >= 1) && (w + 1 < Wd);
  const int rs = Wd * Cin;
  for (int ci = 0; ci < Cin; ci++) {
    float patch[3][3];
    if (interior) {
      const float* xp = x + ((b * H + (h - 1)) * Wd + (w - 1)) * Cin + ci;
#pragma unroll
      for (int rr = 0; rr < 3; rr++)
#pragma unroll
        for (int cc = 0; cc < 3; cc++)
          patch[rr][cc] = xp[rr * rs + cc * Cin];
    } else {
#pragma unroll
      for (int rr = 0; rr < 3; rr++) {
        int ih = h - 1 + rr;
#pragma unroll
        for (int cc = 0; cc < 3; cc++) {
          int iw = w - 1 + cc;
          patch[rr][cc] = (ih >= 0 && ih < H && iw >= 0 && iw < Wd)
                              ? x[((b * H + ih) * Wd + iw) * Cin + ci] : 0.0f;
        }
      }
    }
#pragma unroll
    for (int ky = 0; ky < 3; ky++) {
#pragma unroll
      for (int kx = 0; kx < 3; kx++) {
        const float* wp = W + (((ky * 3 + kx) * Cin) + ci) * Cout + co;
        float4 wa = *(const float4*)wp;
        float4 wb = *(const float4*)(wp + 4);
        float w8[8] = {wa.x, wa.y, wa.z, wa.w, wb.x, wb.y, wb.z, wb.w};
        float iv = patch[ky][kx];
#pragma unroll
        for (int cc = 0; cc < 8; cc++) acc[cc] += iv * w8[cc];
      }
    }
  }
  float* yp = y + ((b * H + h) * Wd + w) * Cout + co;
#pragma unroll
  for (int cc = 0; cc < 8; cc++)
    yp[cc] = fmaxf(acc[cc] + bias[co + cc], 0.0f);
}

// ---------------- generic tiled SGEMM: C = A@B (+D) (+bias) ----------------
// amode 0: A[row*lda+k].  amode 1: A row = embedding[labels[b*151+t]], row=t*16+b, K=80.
// cmode 0: C[row*ldc+col].  cmode 1: logits layout out[(b*150+t)*504+col], row=t*16+b.
__global__ __launch_bounds__(256) void sgemm(
    const float* __restrict__ A, int lda,
    const float* __restrict__ Bm, int ldb,
    float* __restrict__ C, int ldc,
    const float* __restrict__ bias,
    const float* __restrict__ Dadd, int ldd,
    int M, int N, int K, int amode, int cmode,
    const int* __restrict__ labels, const float* __restrict__ emb)
{
  __shared__ float As[16][68];
  __shared__ float Bs[16][68];
  int tid = threadIdx.x;
  int tx = tid & 15, ty = tid >> 4;
  int m0 = blockIdx.y * 64, n0 = blockIdx.x * 64;
  float acc[4][4];
#pragma unroll
  for (int i = 0; i < 4; i++)
#pragma unroll
    for (int j = 0; j < 4; j++) acc[i][j] = 0.0f;
  int am = tid >> 2;
  int ak4 = (tid & 3) * 4;
  int bk = tid >> 4;
  int bn4 = (tid & 15) * 4;
  for (int k0 = 0; k0 < K; k0 += 16) {
    float4 av = make_float4(0.f, 0.f, 0.f, 0.f);
    int row = m0 + am;
    if (row < M) {
      const float* ap;
      if (amode == 0) {
        ap = A + (size_t)row * lda + k0 + ak4;
      } else {
        int t = row >> 4, b = row & 15;
        int lbl = labels[b * TLAB + t];
        ap = emb + lbl * 80 + k0 + ak4;
      }
      av = *(const float4*)ap;
    }
    As[ak4 + 0][am] = av.x; As[ak4 + 1][am] = av.y;
    As[ak4 + 2][am] = av.z; As[ak4 + 3][am] = av.w;
    float4 bv = make_float4(0.f, 0.f, 0.f, 0.f);
    int col = n0 + bn4;
    const float* bp = Bm + (size_t)(k0 + bk) * ldb + col;
    if (col + 3 < N) {
      bv = *(const float4*)bp;
    } else if (col < N) {
      bv.x = bp[0];
      if (col + 1 < N) bv.y = bp[1];
      if (col + 2 < N) bv.z = bp[2];
    }
    *(float4*)&Bs[bk][bn4] = bv;
    __syncthreads();
#pragma unroll
    for (int kk = 0; kk < 16; kk++) {
      float4 a4 = *(const float4*)&As[kk][ty * 4];
      float4 b4 = *(const float4*)&Bs[kk][tx * 4];
      float avv[4] = {a4.x, a4.y, a4.z, a4.w};
      float bvv[4] = {b4.x, b4.y, b4.z, b4.w};
#pragma unroll
      for (int i = 0; i < 4; i++)
#pragma unroll
        for (int j = 0; j < 4; j++) acc[i][j] += avv[i] * bvv[j];
    }
    __syncthreads();
  }
#pragma unroll
  for (int i = 0; i < 4; i++) {
    int row = m0 + ty * 4 + i;
    if (row >= M) continue;
#pragma unroll
    for (int j = 0; j < 4; j++) {
      int col = n0 + tx * 4 + j;
      if (col >= N) continue;
      float v = acc[i][j];
      if (Dadd) v += Dadd[(size_t)row * ldd + col];
      if (bias) v += bias[col];
      if (cmode == 0) {
        C[(size_t)row * ldc + col] = v;
      } else {
        int t = row >> 4, b = row & 15;
        C[((size_t)b * TDEC + t) * 504 + col] = v;
      }
    }
  }
}

// ---------------- encoder LSTM recurrent step (both directions) ------------
// thread: (dir, nq, u) -> 4 batch rows x 4 gates.  16384 threads.
__global__ __launch_bounds__(256) void enc_step(
    const float* __restrict__ Zfw, const float* __restrict__ Zbw,
    const float* __restrict__ Whfw, const float* __restrict__ Whbw,
    const float* __restrict__ hin, float* __restrict__ hout,
    float* __restrict__ cst, float* __restrict__ mem, int t)
{
  int gid = blockIdx.x * 256 + threadIdx.x;
  int u = gid & 255;
  int nq = (gid >> 8) & 31;
  int dir = (gid >> 13) & 1;
  const float* Wh = dir ? Whbw : Whfw;
  const float* Z = dir ? Zbw : Zfw;
  int wp = dir ? (63 - t) : t;
  int n0 = nq * 4;
  float acc[4][4];
#pragma unroll
  for (int nn = 0; nn < 4; nn++)
#pragma unroll
    for (int g = 0; g < 4; g++)
      acc[nn][g] = Z[((size_t)((n0 + nn) * 64 + wp)) * 1024 + g * 256 + u];
  const float* hb = hin + dir * 32768;
  for (int k = 0; k < 256; k += 4) {
    float w[4][4];
#pragma unroll
    for (int kk = 0; kk < 4; kk++)
#pragma unroll
      for (int g = 0; g < 4; g++)
        w[kk][g] = Wh[(size_t)(k + kk) * 1024 + g * 256 + u];
#pragma unroll
    for (int nn = 0; nn < 4; nn++) {
      float4 hv = *(const float4*)(hb + (n0 + nn) * 256 + k);
#pragma unroll
      for (int g = 0; g < 4; g++)
        acc[nn][g] += hv.x * w[0][g] + hv.y * w[1][g] + hv.z * w[2][g] + hv.w * w[3][g];
    }
  }
#pragma unroll
  for (int nn = 0; nn < 4; nn++) {
    int n = n0 + nn;
    int ci = dir * 32768 + n * 256 + u;
    float cold = cst[ci];
    float cn = sigm(acc[nn][2] + 1.0f) * cold + sigm(acc[nn][0]) * tanhfast(acc[nn][1]);
    float hn = sigm(acc[nn][3]) * tanhfast(cn);
    cst[ci] = cn;
    hout[ci] = hn;
    int b = n >> 3, hp = n & 7;
    mem[((size_t)(b * 512 + hp * 64 + wp)) * 512 + dir * 256 + u] = hn;
  }
}

// ---------------- decoder LSTM cell ----------------------------------------
// z = Zemb[t] + [h_prev|ctxB_prev] @ Wcat.  64 blocks x 256 threads.
__global__ __launch_bounds__(256) void dec_cell(
    const float* __restrict__ Wcat, const float* __restrict__ zembt,
    const float* __restrict__ hprev, float* __restrict__ histt,
    float* __restrict__ cst)
{
  __shared__ float part[16][256];
  int tid = threadIdx.x;
  int ul = tid & 7;
  int g = (tid >> 3) & 3;
  int ks = tid >> 5;
  int uc = blockIdx.x;
  int col = g * 512 + uc * 8 + ul;
  float acc[16];
#pragma unroll
  for (int b = 0; b < 16; b++) acc[b] = 0.0f;
  int kbase = ks * 128;
  for (int kc = 0; kc < 128; kc += 8) {
    int k = kbase + kc;
    float w[8];
#pragma unroll
    for (int i = 0; i < 8; i++) w[i] = Wcat[(size_t)(k + i) * 2048 + col];
#pragma unroll
    for (int b = 0; b < 16; b++) {
      const float* xp = hprev + b * 1024 + k;
      float4 x0 = *(const float4*)xp;
      float4 x1 = *(const float4*)(xp + 4);
      acc[b] += x0.x * w[0] + x0.y * w[1] + x0.z * w[2] + x0.w * w[3]
              + x1.x * w[4] + x1.y * w[5] + x1.z * w[6] + x1.w * w[7];
    }
  }
#pragma unroll
  for (int b = 0; b < 16; b++) part[b][tid] = acc[b];
  __syncthreads();
  if (tid < 128) {
    int b = tid >> 3;
    int ul2 = tid & 7;
    int u = uc * 8 + ul2;
    float z[4];
#pragma unroll
    for (int gg = 0; gg < 4; gg++) {
      float s = zembt[b * 2048 + gg * 512 + u];
#pragma unroll
      for (int k2 = 0; k2 < 8; k2++) s += part[b][k2 * 32 + gg * 8 + ul2];
      z[gg] = s;
    }
    float cold = cst[b * 512 + u];
    float cn = sigm(z[2] + 1.0f) * cold + sigm(z[0]) * tanhfast(z[1]);
    float hn = sigm(z[3]) * tanhfast(cn);
    cst[b * 512 + u] = cn;
    histt[b * 1024 + u] = hn;
  }
}

// ---------------- q = h @ Wq ------------------------------------------------
__global__ __launch_bounds__(256) void dec_q(
    const float* __restrict__ h, const float* __restrict__ Wq,
    float* __restrict__ q)
{
  __shared__ float part[16][256];
  int tid = threadIdx.x;
  int jl = tid & 15, ks = tid >> 4;
  int j = blockIdx.x * 16 + jl;
  float acc[16];
#pragma unroll
  for (int b = 0; b < 16; b++) acc[b] = 0.0f;
  int kbase = ks * 32;
  for (int kc = 0; kc < 32; kc += 4) {
    int k = kbase + kc;
    float w[4];
#pragma unroll
    for (int i = 0; i < 4; i++) w[i] = Wq[(size_t)(k + i) * 512 + j];
#pragma unroll
    for (int b = 0; b < 16; b++) {
      float4 hv = *(const float4*)(h + b * 1024 + k);
      acc[b] += hv.x * w[0] + hv.y * w[1] + hv.z * w[2] + hv.w * w[3];
    }
  }
#pragma unroll
  for (int b = 0; b < 16; b++) part[b][tid] = acc[b];
  __syncthreads();
  {
    int b = tid >> 4, jl2 = tid & 15;
    float s = 0.0f;
#pragma unroll
    for (int k2 = 0; k2 < 16; k2++) s += part[b][k2 * 16 + jl2];
    q[b * 512 + blockIdx.x * 16 + jl2] = s;
  }
}

// ---------------- score[b][l] = v . tanh(keys[b][l] + q[b]) ----------------
__global__ __launch_bounds__(256) void dec_score(
    const float* __restrict__ keys, const float* __restrict__ q,
    const float* __restrict__ vatt, float* __restrict__ scores)
{
  int tid = threadIdx.x;
  int dk = tid & 7, lc = tid >> 3;
  int b = blockIdx.x >> 4;
  int l = (blockIdx.x & 15) * 32 + lc;
  const float* kp = keys + ((size_t)b * 512 + l) * 512;
  const float* qp = q + b * 512;
  float acc = 0.0f;
#pragma unroll
  for (int i = 0; i < 16; i++) {
    int d = (i * 8 + dk) * 4;
    float4 kv = *(const float4*)(kp + d);
    float4 qv = *(const float4*)(qp + d);
    float4 vv = *(const float4*)(vatt + d);
    acc += tanhfast(kv.x + qv.x) * vv.x + tanhfast(kv.y + qv.y) * vv.y
         + tanhfast(kv.z + qv.z) * vv.z + tanhfast(kv.w + qv.w) * vv.w;
  }
  acc += __shfl_xor(acc, 1, 64);
  acc += __shfl_xor(acc, 2, 64);
  acc += __shfl_xor(acc, 4, 64);
  if (dk == 0) scores[b * 512 + l] = acc;
}

// ---------------- softmax(scores) and ctxB = align @ memB ------------------
__global__ __launch_bounds__(256) void dec_ctxB(
    const float* __restrict__ scores, const float* __restrict__ memB,
    float* __restrict__ histt)
{
  __shared__ float ez[512];
  __shared__ float red[256];
  __shared__ float part[8][33];
  int tid = threadIdx.x;
  int b = blockIdx.x >> 4;
  int j0 = (blockIdx.x & 15) * 32;
  float s0 = __expf(scores[b * 512 + tid * 2]);      // scores bounded ~|20|, safe
  float s1 = __expf(scores[b * 512 + tid * 2 + 1]);
  ez[tid * 2] = s0; ez[tid * 2 + 1] = s1;
  red[tid] = s0 + s1;
  __syncthreads();
  for (int s = 128; s > 0; s >>= 1) {
    if (tid < s) red[tid] += red[tid + s];
    __syncthreads();
  }
  float den = red[0];
  int jl = tid & 31, ls = tid >> 5;
  const float* mp = memB + (size_t)b * 512 * 512 + j0 + jl;
  float acc = 0.0f;
  int lb = ls * 64;
#pragma unroll 8
  for (int li = 0; li < 64; li++) {
    acc += ez[lb + li] * mp[(size_t)(lb + li) * 512];
  }
  part[ls][jl] = acc;
  __syncthreads();
  if (tid < 32) {
    float s = 0.0f;
#pragma unroll
    for (int l2 = 0; l2 < 8; l2++) s += part[l2][tid];
    histt[b * 1024 + 512 + j0 + tid] = s / den;
  }
}

// ---------------------------------------------------------------------------
extern "C" void kernel_launch(void* const* d_in, const int* in_sizes, int n_in,
                              void* d_out, int out_size, void* d_ws, size_t ws_size,
                              hipStream_t stream) {
  (void)in_sizes; (void)n_in; (void)out_size; (void)ws_size;
  const float* inp   = (const float*)d_in[0];
  const int*   labels= (const int*)  d_in[1];
  const float* ck1 = (const float*)d_in[3];
  const float* cb1 = (const float*)d_in[4];
  const float* ck2 = (const float*)d_in[5];
  const float* cb2 = (const float*)d_in[6];
  const float* ck3 = (const float*)d_in[7];
  const float* cb3 = (const float*)d_in[8];
  const float* ck4 = (const float*)d_in[9];
  const float* cb4 = (const float*)d_in[10];
  const float* Wfw = (const float*)d_in[11];
  const float* bfw = (const float*)d_in[12];
  const float* Wbw = (const float*)d_in[13];
  const float* bbw = (const float*)d_in[14];
  const float* Wdec= (const float*)d_in[15];
  const float* bdec= (const float*)d_in[16];
  const float* Wmem= (const float*)d_in[17];
  const float* Wq  = (const float*)d_in[18];
  const float* vatt= (const float*)d_in[19];
  const float* Wattn=(const float*)d_in[20];
  const float* Wout= (const float*)d_in[21];
  const float* bout= (const float*)d_in[22];
  const float* emb = (const float*)d_in[23];
  float* out = (float*)d_out;
  float* ws  = (float*)d_ws;

  // workspace layout (floats); total 40,599,552 floats = ~162 MB
  const size_t OFF_P1    = 0;              // 8,388,608   (later: Zfw, then Zemb)
  const size_t OFF_P2    = 8388608;        // 4,194,304   (later: Zbw spans P2+half of C3)
  const size_t OFF_C3    = 12582912;       // 8,388,608
  const size_t OFF_HIST  = 16777216;       // 2,457,600   (inside dead C3, after Zbw)
  const size_t OFF_P4    = 20971520;       // 4,194,304
  const size_t OFF_MEM   = 25165824;       // 4,194,304
  const size_t OFF_KEYS  = 29360128;       // 4,194,304
  const size_t OFF_MEMB  = 33554432;       // 4,194,304
  const size_t OFF_WCAT  = 37748736;       // 2,097,152
  const size_t OFF_WCAT2 = 39845888;       //   516,096
  const size_t OFF_HA    = 40361984;       //    65,536
  const size_t OFF_HB    = 40427520;       //    65,536
  const size_t OFF_CENC  = 40493056;       //    65,536
  const size_t OFF_CDEC  = 40558592;       //     8,192
  const size_t OFF_Q     = 40566784;       //     8,192
  const size_t OFF_SC    = 40574976;       //     8,192
  const size_t OFF_ZERO  = 40583168;       //    16,384

  float* p1   = ws + OFF_P1;
  float* p2   = ws + OFF_P2;
  float* c3   = ws + OFF_C3;
  float* p4   = ws + OFF_P4;
  float* Zfw  = ws + OFF_P1;     // alias, p1 dead
  float* Zbw  = ws + OFF_P2;     // alias, p2+front of c3 dead
  float* Zemb = ws + OFF_P1;     // alias, Zfw dead after encoder
  float* hist = ws + OFF_HIST;
  float* memv = ws + OFF_MEM;
  float* keys = ws + OFF_KEYS;
  float* memB = ws + OFF_MEMB;
  float* Wcat = ws + OFF_WCAT;
  float* Wcat2= ws + OFF_WCAT2;
  float* hA   = ws + OFF_HA;
  float* hB   = ws + OFF_HB;
  float* cenc = ws + OFF_CENC;
  float* cdec = ws + OFF_CDEC;
  float* qbuf = ws + OFF_Q;
  float* scor = ws + OFF_SC;
  float* zerob= ws + OFF_ZERO;

  hipMemsetAsync(hA,    0, 65536 * 4, stream);
  hipMemsetAsync(cenc,  0, 65536 * 4, stream);
  hipMemsetAsync(cdec,  0, 8192 * 4, stream);
  hipMemsetAsync(zerob, 0, 16384 * 4, stream);

  // CNN
  conv_pool<<<4096, 256, 0, stream>>>(inp, ck1, cb1, p1, 64, 512, 1, 64);
  conv_pool<<<2048, 256, 0, stream>>>(p1, ck2, cb2, p2, 32, 256, 64, 128);
  conv_nopool<<<4096, 256, 0, stream>>>(p2, ck3, cb3, c3, 16, 128, 128, 256);
  conv_pool<<<2048, 256, 0, stream>>>(c3, ck4, cb4, p4, 16, 128, 256, 512);

  // encoder input-side GEMMs (all timesteps at once): Z = P @ Wx + b
  {
    dim3 g(16, 128);
    sgemm<<<g, 256, 0, stream>>>(p4, 512, Wfw, 1024, Zfw, 1024, bfw, nullptr, 0,
                                 8192, 1024, 512, 0, 0, nullptr, nullptr);
    sgemm<<<g, 256, 0, stream>>>(p4, 512, Wbw, 1024, Zbw, 1024, bbw, nullptr, 0,
                                 8192, 1024, 512, 0, 0, nullptr, nullptr);
  }
  // encoder recurrence (writes memory tensor directly)
  for (int t = 0; t < 64; t++) {
    const float* hin = (t & 1) ? hB : hA;
    float* hout = (t & 1) ? hA : hB;
    enc_step<<<64, 256, 0, stream>>>(Zfw, Zbw, Wfw + 512 * 1024, Wbw + 512 * 1024,
                                     hin, hout, cenc, memv, t);
  }

  // attention precomputes
  {
    dim3 g(8, 128);
    sgemm<<<g, 256, 0, stream>>>(memv, 512, Wmem, 512, keys, 512, nullptr, nullptr, 0,
                                 8192, 512, 512, 0, 0, nullptr, nullptr);
    sgemm<<<g, 256, 0, stream>>>(memv, 512, Wattn + 512 * 512, 512, memB, 512, nullptr, nullptr, 0,
                                 8192, 512, 512, 0, 0, nullptr, nullptr);
  }
  // Wcat: rows0-511 = Wdec_h + W1@Wdec_attn ; rows512-1023 = Wdec_attn
  {
    dim3 g(32, 8);
    sgemm<<<g, 256, 0, stream>>>(Wattn, 512, Wdec + 80 * 2048, 2048, Wcat, 2048,
                                 nullptr, Wdec + 592 * 2048, 2048,
                                 512, 2048, 512, 0, 0, nullptr, nullptr);
    hipMemcpyAsync(Wcat + 512 * 2048, Wdec + 80 * 2048, (size_t)512 * 2048 * 4,
                   hipMemcpyDeviceToDevice, stream);
  }
  // Wcat2: rows0-511 = W1@Wout ; rows512-1023 = Wout
  {
    dim3 g(8, 8);
    sgemm<<<g, 256, 0, stream>>>(Wattn, 512, Wout, 504, Wcat2, 504,
                                 nullptr, nullptr, 0, 512, 504, 512, 0, 0, nullptr, nullptr);
    hipMemcpyAsync(Wcat2 + 512 * 504, Wout, (size_t)512 * 504 * 4,
                   hipMemcpyDeviceToDevice, stream);
  }
  // Zemb[t*16+b] = e @ Wdec_e + bdec (embedding gather inside)
  {
    dim3 g(32, 38);
    sgemm<<<g, 256, 0, stream>>>(nullptr, 0, Wdec, 2048, Zemb, 2048, bdec, nullptr, 0,
                                 2400, 2048, 80, 1, 0, labels, emb);
  }

  // decoder recurrence
  for (int t = 0; t < TDEC; t++) {
    const float* hprev = (t == 0) ? zerob : (hist + (size_t)(t - 1) * 16384);
    float* ht = hist + (size_t)t * 16384;
    dec_cell<<<64, 256, 0, stream>>>(Wcat, Zemb + (size_t)t * 32768, hprev, ht, cdec);
    dec_q<<<32, 256, 0, stream>>>(ht, Wq, qbuf);
    dec_score<<<256, 256, 0, stream>>>(keys, qbuf, vatt, scor);
    dec_ctxB<<<256, 256, 0, stream>>>(scor, memB, ht);
  }

  // logits = [h|ctxB] @ Wcat2 + bout, written straight into (b,t,v) layout
  {
    dim3 g(8, 38);
    sgemm<<<g, 256, 0, stream>>>(hist, 1024, Wcat2, 504, out, 504, bout, nullptr, 0,
                                 2400, 504, 1024, 0, 1, nullptr, nullptr);
  }
}